// Round 11
// baseline (556.507 us; speedup 1.0000x reference)
//
#include <hip/hip_runtime.h>
#include <hip/hip_fp16.h>
#include <math.h>

#define N_NODES 40000
#define N_EDGES 640000
#define FIN 64
#define HID 128
#define OUTDIM 64
#define HEADS 4
#define NGROUPS 64
#define NCOLS 512   // HEADS*HID

typedef _Float16 half8 __attribute__((ext_vector_type(8)));
typedef float f32x4 __attribute__((ext_vector_type(4)));

__device__ __forceinline__ float lrelu(float x) { return x > 0.f ? x : 0.2f * x; }

__device__ __forceinline__ void wave_lds_fence() {
    asm volatile("s_waitcnt lgkmcnt(0)" ::: "memory");
}

// ---- fused prep: x->fp16 | fragment-major weight swizzle (3 layers) | vtab ----
#define PREP_X4   (N_NODES * FIN / 4)                 // 640000
#define PREP_WSWZ 20480                               // 4096 + 8192 + 8192
#define PREP_V    2560                                // (FIN + 2*HID) * 8
__global__ void prep_kernel(const float* __restrict__ x, __half* __restrict__ x16,
                            const float* __restrict__ W0, const float* __restrict__ W1,
                            const float* __restrict__ W2,
                            _Float16* __restrict__ F0, _Float16* __restrict__ F1,
                            _Float16* __restrict__ F2,
                            const float* __restrict__ as0, const float* __restrict__ ad0,
                            const float* __restrict__ as1, const float* __restrict__ ad1,
                            const float* __restrict__ as2, const float* __restrict__ ad2,
                            float* __restrict__ v0, float* __restrict__ v1,
                            float* __restrict__ v2) {
    int id = blockIdx.x * 256 + threadIdx.x;
    if (id < PREP_X4) {
        int i4 = id * 4;
        float4 v = *(const float4*)(x + i4);
        __half2 a = __floats2half2_rn(v.x, v.y);
        __half2 b = __floats2half2_rn(v.z, v.w);
        *(__half2*)(x16 + i4)     = a;
        *(__half2*)(x16 + i4 + 2) = b;
        return;
    }
    id -= PREP_X4;
    if (id < PREP_WSWZ) {
        const float* W; _Float16* F; int K;
        if (id < 4096)       { W = W0; F = F0; K = FIN; }
        else if (id < 12288) { W = W1; F = F1; K = HID; id -= 4096; }
        else                 { W = W2; F = F2; K = HID; id -= 12288; }
        int lane = id & 63;
        int blob = id >> 6;
        int nk = K / 32;
        int k0g = blob % nk;
        int cb  = blob / nk;
        int col = cb * 16 + (lane & 15);
        int kb  = k0g * 32 + (lane >> 4) * 8;
        half8 v;
        #pragma unroll
        for (int e = 0; e < 8; ++e)
            v[e] = (_Float16)W[(size_t)(kb + e) * NCOLS + col];
        *(half8*)(F + (size_t)blob * 512 + lane * 8) = v;
        return;
    }
    id -= PREP_WSWZ;
    if (id < PREP_V) {
        const float* W; const float* as_; const float* ad_; float* v; int j = id;
        if (j < FIN * 8)              { W = W0; as_ = as0; ad_ = ad0; v = v0; }
        else if (j < (FIN + HID) * 8) { W = W1; as_ = as1; ad_ = ad1; v = v1; j -= FIN * 8; }
        else                          { W = W2; as_ = as2; ad_ = ad2; v = v2; j -= (FIN + HID) * 8; }
        int k = j >> 3, sd = (j >> 2) & 1, h = j & 3;
        const float* av = sd ? ad_ : as_;
        float acc = 0.f;
        for (int c = 0; c < HID; ++c)
            acc += W[(size_t)k * NCOLS + h * HID + c] * av[h * HID + c];
        v[k * 8 + sd * 4 + h] = acc;
    }
}

// ---------------- CSR build ----------------
__global__ void deg_count_kernel(const int* __restrict__ ei, int* deg) {
    int e = blockIdx.x * blockDim.x + threadIdx.x;
    if (e < N_EDGES) atomicAdd(&deg[ei[N_EDGES + e]], 1);
}

__global__ void scan1_kernel(const int* __restrict__ deg, int* offsets, int* partial) {
    __shared__ int buf[256];
    int t = threadIdx.x;
    int i = blockIdx.x * 256 + t;
    int v = (i < N_NODES) ? deg[i] + 1 : 0;   // +1 = self loop
    buf[t] = v;
    __syncthreads();
    for (int off = 1; off < 256; off <<= 1) {
        int y = (t >= off) ? buf[t - off] : 0;
        __syncthreads();
        buf[t] += y;
        __syncthreads();
    }
    if (i < N_NODES) offsets[i] = buf[t] - v;       // local exclusive
    if (t == 255) partial[blockIdx.x] = buf[255];
}

__global__ void scan2_kernel(int* partial, int nb) {
    __shared__ int buf[256];
    int t = threadIdx.x;
    int v = (t < nb) ? partial[t] : 0;
    buf[t] = v;
    __syncthreads();
    for (int off = 1; off < 256; off <<= 1) {
        int y = (t >= off) ? buf[t - off] : 0;
        __syncthreads();
        buf[t] += y;
        __syncthreads();
    }
    if (t < nb) partial[t] = buf[t] - v;            // exclusive block prefix
}

__global__ void scan3_kernel(int* offsets, int* pos, const int* __restrict__ partial) {
    int i = blockIdx.x * 256 + threadIdx.x;
    if (i < N_NODES) {
        int o = offsets[i] + partial[i >> 8];
        offsets[i] = o;
        pos[i] = o;
    }
    if (i == 0) offsets[N_NODES] = N_EDGES + N_NODES;
}

__global__ void scatter_kernel(const int* __restrict__ ei, int* pos, int* csr_src) {
    int i = blockIdx.x * blockDim.x + threadIdx.x;
    if (i < N_EDGES) {
        int s = ei[i];
        int d = ei[N_EDGES + i];
        csr_src[atomicAdd(&pos[d], 1)] = s;
    } else if (i < N_EDGES + N_NODES) {
        int nn = i - N_EDGES;
        csr_src[atomicAdd(&pos[nn], 1)] = nn;
    }
}

// ------- MFMA GEMM: 64x512 block tile; C written HEAD-MAJOR [4][N][128] ---------
template <int K>
__global__ __launch_bounds__(512) void gemm_f16_kernel(const __half* __restrict__ A,
                                                       const _Float16* __restrict__ Wf,
                                                       const float* __restrict__ vtab,
                                                       __half* __restrict__ C,
                                                       float* __restrict__ ssrc,
                                                       float* __restrict__ sdst) {
    __shared__ _Float16 As[64][K + 8];
    __shared__ _Float16 tb[64][264];     // C staging: 64 rows x 256 cols (+pad)
    __shared__ float vs[K * 8];
    int bm = blockIdx.x * 64;
    int t = threadIdx.x;
    int lane = t & 63;
    int w = t >> 6;
    int wm = w >> 2;        // 0..1
    int wn = w & 3;         // 0..3
    int lr = lane & 15;
    int lk = (lane >> 4) * 8;

    for (int i = t; i < K * 8; i += 512) vs[i] = vtab[i];
    if (K == 64) {
        int row = t >> 3, k8 = (t & 7) * 8;
        uint4 av = *(const uint4*)(A + (size_t)(bm + row) * 64 + k8);
        *(uint4*)&As[row][k8] = av;
    } else {  // K == 128
        int row = t >> 4, k8 = (t & 15) * 8;
        #pragma unroll
        for (int rr = 0; rr < 64; rr += 32) {
            uint4 av = *(const uint4*)(A + (size_t)(bm + row + rr) * 128 + k8);
            *(uint4*)&As[row + rr][k8] = av;
        }
    }
    __syncthreads();

    constexpr int NK = K / 32;
    f32x4 acc[2][8] = {};
    #pragma unroll
    for (int k0g = 0; k0g < NK; ++k0g) {
        half8 af0 = *(const half8*)&As[wm * 32 + lr][k0g * 32 + lk];
        half8 af1 = *(const half8*)&As[wm * 32 + 16 + lr][k0g * 32 + lk];
        #pragma unroll
        for (int nn = 0; nn < 8; ++nn) {
            int cb = wn * 8 + nn;
            half8 bf = *(const half8*)(Wf + ((size_t)(cb * NK + k0g) << 9) + lane * 8);
            acc[0][nn] = __builtin_amdgcn_mfma_f32_16x16x32_f16(af0, bf, acc[0][nn], 0, 0, 0);
            acc[1][nn] = __builtin_amdgcn_mfma_f32_16x16x32_f16(af1, bf, acc[1][nn], 0, 0, 0);
        }
    }

    // ---- fused scores: node = t>>3 (64 nodes), j = t&7 (4 src + 4 dst heads) ----
    {
        int node = t >> 3, j = t & 7;
        float sacc = 0.f;
        #pragma unroll 2
        for (int k0 = 0; k0 < K; k0 += 8) {
            half8 hv = *(const half8*)&As[node][k0];
            #pragma unroll
            for (int e = 0; e < 8; ++e)
                sacc += (float)hv[e] * vs[(k0 + e) * 8 + j];
        }
        if (j < 4) ssrc[(bm + node) * 4 + j] = sacc;
        else       sdst[(bm + node) * 4 + (j - 4)] = sacc;
    }

    // ---- C write: 2 rounds; stores go to head-major slices [head][N][128] ----
    int lg = lane >> 4;
    #pragma unroll
    for (int rnd = 0; rnd < 2; ++rnd) {
        __syncthreads();
        if ((wn >> 1) == rnd) {
            int cbase = (wn & 1) * 128;
            #pragma unroll
            for (int m = 0; m < 2; ++m) {
                int row = wm * 32 + m * 16 + lg * 4;
                #pragma unroll
                for (int nn = 0; nn < 8; ++nn) {
                    int col = cbase + nn * 16 + lr;
                    #pragma unroll
                    for (int r = 0; r < 4; ++r)
                        tb[row + r][col] = (_Float16)acc[m][nn][r];
                }
            }
        }
        __syncthreads();
        {
            int row = t >> 3;
            int c0 = (t & 7) * 32;
            int gcol = rnd * 256 + c0;
            int hh = gcol >> 7;          // head 0..3
            int cc = gcol & 127;         // 0,32,64,96
            half8 v0 = *(const half8*)&tb[row][c0];
            half8 v1 = *(const half8*)&tb[row][c0 + 8];
            half8 v2 = *(const half8*)&tb[row][c0 + 16];
            half8 v3 = *(const half8*)&tb[row][c0 + 24];
            _Float16* cp = (_Float16*)C + (size_t)hh * N_NODES * HID
                         + (size_t)(bm + row) * HID + cc;
            *(half8*)(cp)      = v0;
            *(half8*)(cp + 8)  = v1;
            *(half8*)(cp + 16) = v2;
            *(half8*)(cp + 24) = v3;
        }
    }
}

// ---- head-partitioned aggregate: one wave per (node, head), XCD-pinned heads ----
// grid = 40000 blocks (10000 node-groups x 4 heads); bid%8 -> XCD; head = (bid%8)>>1
// xh/part are head-major [4][N][128]. Each XCD only touches its head's 10MB slice.
__device__ __forceinline__ void accum4(float* acc, uint2 u, float a) {
    __half2 h0 = *(__half2*)&u.x;
    __half2 h1 = *(__half2*)&u.y;
    float2 f0 = __half22float2(h0);
    float2 f1 = __half22float2(h1);
    acc[0] += a * f0.x;
    acc[1] += a * f0.y;
    acc[2] += a * f1.x;
    acc[3] += a * f1.y;
}

__global__ __launch_bounds__(256) void aggregate_h_kernel(const __half* __restrict__ xh,
                                                          const float* __restrict__ s_src,
                                                          const float* __restrict__ s_dst,
                                                          const int* __restrict__ offsets,
                                                          const int* __restrict__ csr_src,
                                                          __half* __restrict__ part) {
    int bid = blockIdx.x;
    int p = bid & 7;
    int h = p >> 1;
    int sub = p & 1;
    int grp = (bid >> 3) * 2 + sub;       // 0..9999
    int wv = threadIdx.x >> 6;
    int lane = threadIdx.x & 63;
    int n = grp * 4 + wv;
    int start = offsets[n], end = offsets[n + 1];
    int deg = end - start;
    float sdh = s_dst[n * 4 + h];

    __shared__ int   roff[4][64];
    __shared__ float al[4][64];

    const char* tab = (const char*)(xh + (size_t)h * N_NODES * HID);
    const char* xb = tab + (lane & 31) * 8;   // 8B (4 halves) per lane within 256B row
    int epar = lane >> 5;                      // half-wave edge parity

    float acc[4] = {0.f, 0.f, 0.f, 0.f};

    if (deg <= 64) {
        bool act = lane < deg;
        int src = act ? csr_src[start + lane] : 0;
        float e = act ? lrelu(s_src[src * 4 + h] + sdh) : -1e30f;
        float m = e;
        #pragma unroll
        for (int o = 32; o > 0; o >>= 1) m = fmaxf(m, __shfl_xor(m, o));
        float pr = __expf(e - m);     // inactive: exp(-inf)=0
        float s = pr;
        #pragma unroll
        for (int o = 32; o > 0; o >>= 1) s += __shfl_xor(s, o);
        roff[wv][lane] = src << 8;    // byte offset into head slice (256B rows)
        al[wv][lane] = pr / s;
        wave_lds_fence();

        for (int j = 0; j < deg; j += 4) {
            int e0 = j + epar;        // half-wave 0: j, j+2 ; half-wave 1: j+1, j+3
            int e1 = j + 2 + epar;    // indices <= 63; beyond-deg entries have al=0
            float a0 = al[wv][e0], a1 = al[wv][e1];
            uint2 u0 = *(const uint2*)(xb + roff[wv][e0]);
            uint2 u1 = *(const uint2*)(xb + roff[wv][e1]);
            accum4(acc, u0, a0);
            accum4(acc, u1, a1);
        }
    } else {
        // generic chunked path (deg > 64), single head
        float m = -1e30f;
        for (int j0 = 0; j0 < deg; j0 += 64) {
            int j = j0 + lane;
            bool act = j < deg;
            int src = act ? csr_src[start + j] : 0;
            float e = act ? lrelu(s_src[src * 4 + h] + sdh) : -1e30f;
            m = fmaxf(m, e);
        }
        #pragma unroll
        for (int o = 32; o > 0; o >>= 1) m = fmaxf(m, __shfl_xor(m, o));
        float s = 0.f;
        for (int j0 = 0; j0 < deg; j0 += 64) {
            int j = j0 + lane;
            bool act = j < deg;
            int src = act ? csr_src[start + j] : 0;
            s += act ? __expf(lrelu(s_src[src * 4 + h] + sdh) - m) : 0.f;
        }
        #pragma unroll
        for (int o = 32; o > 0; o >>= 1) s += __shfl_xor(s, o);
        float inv = 1.f / s;
        for (int j0 = 0; j0 < deg; j0 += 64) {
            int j = j0 + lane;
            bool act = j < deg;
            int src = act ? csr_src[start + j] : 0;
            float av = act ? __expf(lrelu(s_src[src * 4 + h] + sdh) - m) * inv : 0.f;
            roff[wv][lane] = src << 8;
            al[wv][lane] = av;
            wave_lds_fence();
            int cend = min(64, deg - j0);
            for (int j2 = 0; j2 < cend; j2 += 4) {
                int e0 = j2 + epar;
                int e1 = j2 + 2 + epar;
                float a0 = al[wv][e0], a1 = al[wv][e1];
                uint2 u0 = *(const uint2*)(xb + roff[wv][e0]);
                uint2 u1 = *(const uint2*)(xb + roff[wv][e1]);
                accum4(acc, u0, a0);
                accum4(acc, u1, a1);
            }
            wave_lds_fence();
        }
    }

    // combine half-waves (each covered disjoint edges, same channels)
    #pragma unroll
    for (int r = 0; r < 4; ++r) acc[r] += __shfl_xor(acc[r], 32);
    if (lane < 32) {
        __half2 o0 = __floats2half2_rn(acc[0], acc[1]);
        __half2 o1 = __floats2half2_rn(acc[2], acc[3]);
        uint2 pack = {*(uint*)&o0, *(uint*)&o1};
        *(uint2*)((char*)part + (size_t)h * N_NODES * HID * 2
                  + (size_t)n * HID * 2 + lane * 8) = pack;
    }
}

// ---- combine: mean over heads + bias + BN + ReLU -> h16 [N][128] ----
__global__ __launch_bounds__(256) void combine_kernel(const __half* __restrict__ part,
                                                      const float* __restrict__ bias,
                                                      const float* __restrict__ gamma,
                                                      const float* __restrict__ beta,
                                                      __half* __restrict__ h16out) {
    int id = blockIdx.x * 256 + threadIdx.x;   // N*16
    if (id >= N_NODES * 16) return;
    int n = id >> 4, c8 = (id & 15) * 8;
    const _Float16* pp = (const _Float16*)part;
    size_t base = (size_t)n * HID + c8;
    half8 v0 = *(const half8*)(pp + base);
    half8 v1 = *(const half8*)(pp + (size_t)N_NODES * HID + base);
    half8 v2 = *(const half8*)(pp + (size_t)2 * N_NODES * HID + base);
    half8 v3 = *(const half8*)(pp + (size_t)3 * N_NODES * HID + base);
    half8 outv;
    #pragma unroll
    for (int r = 0; r < 8; ++r) {
        int c = c8 + r;
        float o = ((float)v0[r] + (float)v1[r] + (float)v2[r] + (float)v3[r]) * 0.25f
                + bias[c];
        o = o * (gamma[c] * rsqrtf(1.f + 1e-5f)) + beta[c];
        outv[r] = (_Float16)fmaxf(o, 0.f);
    }
    *(half8*)((_Float16*)h16out + base) = outv;
}

// ------- pooling: 2 nodes in flight, uint (2-channel) loads ----------------
__global__ __launch_bounds__(128) void pool_kernel(const __half* __restrict__ h,
                                                   const int* __restrict__ batch,
                                                   float* pooled, float* counts) {
    int t = threadIdx.x;
    int which = t >> 6;
    int c2 = (t & 63) * 2;
    int n0 = blockIdx.x * 256 + which;
    int n1 = min(blockIdx.x * 256 + 256, N_NODES);
    if (n0 >= N_NODES) return;
    int cg = batch[n0];
    float a0 = 0.f, a1 = 0.f, cnt = 0.f;
    for (int n = n0; n < n1; n += 2) {
        int g = batch[n];
        if (g != cg) {
            atomicAdd(&pooled[cg * HID + c2], a0);
            atomicAdd(&pooled[cg * HID + c2 + 1], a1);
            if ((t & 63) == 0) atomicAdd(&counts[cg], cnt);
            a0 = 0.f; a1 = 0.f; cnt = 0.f; cg = g;
        }
        uint u = *(const uint*)(h + (size_t)n * HID + c2);
        __half2 hh = *(__half2*)&u;
        float2 f = __half22float2(hh);
        a0 += f.x; a1 += f.y; cnt += 1.f;
    }
    atomicAdd(&pooled[cg * HID + c2], a0);
    atomicAdd(&pooled[cg * HID + c2 + 1], a1);
    if ((t & 63) == 0) atomicAdd(&counts[cg], cnt);
}

// ---------------- head: mean-divide + fc1 + relu + fc2 ----------------
__global__ __launch_bounds__(128) void head_kernel(const float* __restrict__ pooled,
                                                   const float* __restrict__ counts,
                                                   const float* __restrict__ fc1_w,
                                                   const float* __restrict__ fc1_b,
                                                   const float* __restrict__ fc2_w,
                                                   const float* __restrict__ fc2_b,
                                                   float* __restrict__ out) {
    int gI = blockIdx.x;
    int t = threadIdx.x;
    __shared__ float p[HID], hb[HID];
    p[t] = pooled[gI * HID + t] / fmaxf(counts[gI], 1.f);
    __syncthreads();
    float a = fc1_b[t];
    #pragma unroll 4
    for (int k = 0; k < HID; ++k) a += p[k] * fc1_w[k * HID + t];
    hb[t] = fmaxf(a, 0.f);
    __syncthreads();
    if (t < OUTDIM) {
        float o = fc2_b[t];
        #pragma unroll 4
        for (int k = 0; k < HID; ++k) o += hb[k] * fc2_w[k * OUTDIM + t];
        out[gI * OUTDIM + t] = o;
    }
}

extern "C" void kernel_launch(void* const* d_in, const int* in_sizes, int n_in,
                              void* d_out, int out_size, void* d_ws, size_t ws_size,
                              hipStream_t stream) {
    const float* x     = (const float*)d_in[0];
    const int*   ei    = (const int*)d_in[1];
    const int*   batch = (const int*)d_in[2];
    const float* W[3]  = {(const float*)d_in[3],  (const float*)d_in[9],  (const float*)d_in[15]};
    const float* As[3] = {(const float*)d_in[4],  (const float*)d_in[10], (const float*)d_in[16]};
    const float* Ad[3] = {(const float*)d_in[5],  (const float*)d_in[11], (const float*)d_in[17]};
    const float* Bb[3] = {(const float*)d_in[6],  (const float*)d_in[12], (const float*)d_in[18]};
    const float* Gg[3] = {(const float*)d_in[7],  (const float*)d_in[13], (const float*)d_in[19]};
    const float* Be[3] = {(const float*)d_in[8],  (const float*)d_in[14], (const float*)d_in[20]};
    const float* fc1_w = (const float*)d_in[21];
    const float* fc1_b = (const float*)d_in[22];
    const float* fc2_w = (const float*)d_in[23];
    const float* fc2_b = (const float*)d_in[24];

    char* ws = (char*)d_ws;
    size_t off = 0;
    auto alloc = [&](size_t bytes) {
        void* p = ws + off;
        off = (off + bytes + 255) & ~(size_t)255;
        return p;
    };
    __half* xh     = (__half*)alloc((size_t)N_NODES * NCOLS * 2);   // head-major [4][N][128]
    __half* part   = (__half*)alloc((size_t)N_NODES * NCOLS * 2);   // head-major partials
    __half* x16    = (__half*)alloc((size_t)N_NODES * FIN * 2);
    __half* h16    = (__half*)alloc((size_t)N_NODES * HID * 2);
    _Float16* Wf[3];
    Wf[0] = (_Float16*)alloc((size_t)NCOLS * FIN * 2);
    Wf[1] = (_Float16*)alloc((size_t)NCOLS * HID * 2);
    Wf[2] = (_Float16*)alloc((size_t)NCOLS * HID * 2);
    float* vtab[3];
    vtab[0] = (float*)alloc((size_t)FIN * 8 * 4);
    vtab[1] = (float*)alloc((size_t)HID * 8 * 4);
    vtab[2] = (float*)alloc((size_t)HID * 8 * 4);
    float* ssrc    = (float*)alloc((size_t)N_NODES * HEADS * 4);
    float* sdst    = (float*)alloc((size_t)N_NODES * HEADS * 4);
    int*   deg     = (int*)alloc((size_t)N_NODES * 4);
    int*   offsets = (int*)alloc((size_t)(N_NODES + 1) * 4);
    int*   pos     = (int*)alloc((size_t)N_NODES * 4);
    int*   partial = (int*)alloc((size_t)256 * 4);
    int*   csr     = (int*)alloc((size_t)(N_EDGES + N_NODES) * 4);
    float* pooled  = (float*)alloc((size_t)NGROUPS * HID * 4 + (size_t)NGROUPS * 4);
    float* counts  = pooled + (size_t)NGROUPS * HID;

    // fused prep: x16 + fragment-major weights + vtab
    const int PREP_TOTAL = PREP_X4 + PREP_WSWZ + PREP_V;
    prep_kernel<<<(PREP_TOTAL + 255) / 256, 256, 0, stream>>>(
        x, x16, W[0], W[1], W[2], Wf[0], Wf[1], Wf[2],
        As[0], Ad[0], As[1], Ad[1], As[2], Ad[2], vtab[0], vtab[1], vtab[2]);

    // CSR by dst (with self loops)
    const int NB = (N_NODES + 255) / 256;   // 157
    hipMemsetAsync(deg, 0, (size_t)N_NODES * 4, stream);
    deg_count_kernel<<<(N_EDGES + 255) / 256, 256, 0, stream>>>(ei, deg);
    scan1_kernel<<<NB, 256, 0, stream>>>(deg, offsets, partial);
    scan2_kernel<<<1, 256, 0, stream>>>(partial, NB);
    scan3_kernel<<<NB, 256, 0, stream>>>(offsets, pos, partial);
    scatter_kernel<<<(N_EDGES + N_NODES + 255) / 256, 256, 0, stream>>>(ei, pos, csr);

    // 3 GAT layers
    const __half* Ain = x16;
    for (int l = 0; l < 3; ++l) {
        int K = (l == 0) ? FIN : HID;
        if (K == 64)
            gemm_f16_kernel<64><<<N_NODES / 64, 512, 0, stream>>>(Ain, Wf[l], vtab[l], xh, ssrc, sdst);
        else
            gemm_f16_kernel<128><<<N_NODES / 64, 512, 0, stream>>>(Ain, Wf[l], vtab[l], xh, ssrc, sdst);
        aggregate_h_kernel<<<N_NODES, 256, 0, stream>>>(xh, ssrc, sdst, offsets, csr, part);
        combine_kernel<<<(N_NODES * 16 + 255) / 256, 256, 0, stream>>>(
            part, Bb[l], Gg[l], Be[l], h16);
        Ain = h16;
    }

    // global mean pool + MLP head
    hipMemsetAsync(pooled, 0, (size_t)NGROUPS * HID * 4 + (size_t)NGROUPS * 4, stream);
    pool_kernel<<<(N_NODES + 255) / 256, 128, 0, stream>>>(h16, batch, pooled, counts);
    head_kernel<<<NGROUPS, 128, 0, stream>>>(pooled, counts, fc1_w, fc1_b, fc2_w, fc2_b,
                                             (float*)d_out);
}

// Round 12
// 391.448 us; speedup vs baseline: 1.4217x; 1.4217x over previous
//
#include <hip/hip_runtime.h>
#include <hip/hip_fp16.h>
#include <math.h>

#define N_NODES 40000
#define N_EDGES 640000
#define FIN 64
#define HID 128
#define OUTDIM 64
#define HEADS 4
#define NGROUPS 64
#define NCOLS 512   // HEADS*HID

typedef _Float16 half8 __attribute__((ext_vector_type(8)));
typedef float f32x4 __attribute__((ext_vector_type(4)));

__device__ __forceinline__ float lrelu(float x) { return x > 0.f ? x : 0.2f * x; }

__device__ __forceinline__ void wave_lds_fence() {
    asm volatile("s_waitcnt lgkmcnt(0)" ::: "memory");
}

// ---- fused prep: x->fp16 | Wbig fragment-major swizzle (3 layers) | vtab ----
// Wbig_l[(h*K+k)][c] = 0.25 * W_l[k][h*128+c]  (head-mean folded in), fragment-major
#define PREP_X4   (N_NODES * FIN / 4)                 // 640000
#define PREP_WSWZ 20480                               // 4096 + 8192 + 8192
#define PREP_V    2560                                // (FIN + 2*HID) * 8
__global__ void prep_kernel(const float* __restrict__ x, __half* __restrict__ x16,
                            const float* __restrict__ W0, const float* __restrict__ W1,
                            const float* __restrict__ W2,
                            _Float16* __restrict__ F0, _Float16* __restrict__ F1,
                            _Float16* __restrict__ F2,
                            const float* __restrict__ as0, const float* __restrict__ ad0,
                            const float* __restrict__ as1, const float* __restrict__ ad1,
                            const float* __restrict__ as2, const float* __restrict__ ad2,
                            float* __restrict__ v0, float* __restrict__ v1,
                            float* __restrict__ v2) {
    int id = blockIdx.x * 256 + threadIdx.x;
    if (id < PREP_X4) {
        int i4 = id * 4;
        float4 v = *(const float4*)(x + i4);
        __half2 a = __floats2half2_rn(v.x, v.y);
        __half2 b = __floats2half2_rn(v.z, v.w);
        *(__half2*)(x16 + i4)     = a;
        *(__half2*)(x16 + i4 + 2) = b;
        return;
    }
    id -= PREP_X4;
    if (id < PREP_WSWZ) {
        const float* W; _Float16* F; int Kin;
        if (id < 4096)       { W = W0; F = F0; Kin = FIN; }
        else if (id < 12288) { W = W1; F = F1; Kin = HID; id -= 4096; }
        else                 { W = W2; F = F2; Kin = HID; id -= 12288; }
        int KP = Kin * 4;
        int NKg = KP / 32;
        int lane = id & 63;
        int blob = id >> 6;
        int k0g = blob % NKg;
        int cb  = blob / NKg;
        int col = cb * 16 + (lane & 15);
        int kkb = k0g * 32 + (lane >> 4) * 8;
        half8 v;
        #pragma unroll
        for (int e = 0; e < 8; ++e) {
            int kk = kkb + e;
            int k = kk & (Kin - 1);
            int h = kk / Kin;
            v[e] = (_Float16)(0.25f * W[(size_t)k * NCOLS + h * HID + col]);
        }
        *(half8*)(F + (size_t)blob * 512 + lane * 8) = v;
        return;
    }
    id -= PREP_WSWZ;
    if (id < PREP_V) {
        const float* W; const float* as_; const float* ad_; float* v; int j = id;
        if (j < FIN * 8)              { W = W0; as_ = as0; ad_ = ad0; v = v0; }
        else if (j < (FIN + HID) * 8) { W = W1; as_ = as1; ad_ = ad1; v = v1; j -= FIN * 8; }
        else                          { W = W2; as_ = as2; ad_ = ad2; v = v2; j -= (FIN + HID) * 8; }
        int k = j >> 3, sd = (j >> 2) & 1, h = j & 3;
        const float* av = sd ? ad_ : as_;
        float acc = 0.f;
        for (int c = 0; c < HID; ++c)
            acc += W[(size_t)k * NCOLS + h * HID + c] * av[h * HID + c];
        v[k * 8 + sd * 4 + h] = acc;
    }
}

// ---------------- CSR build ----------------
__global__ void deg_count_kernel(const int* __restrict__ ei, int* deg) {
    int e = blockIdx.x * blockDim.x + threadIdx.x;
    if (e < N_EDGES) atomicAdd(&deg[ei[N_EDGES + e]], 1);
}

__global__ void scan1_kernel(const int* __restrict__ deg, int* offsets, int* partial) {
    __shared__ int buf[256];
    int t = threadIdx.x;
    int i = blockIdx.x * 256 + t;
    int v = (i < N_NODES) ? deg[i] + 1 : 0;   // +1 = self loop
    buf[t] = v;
    __syncthreads();
    for (int off = 1; off < 256; off <<= 1) {
        int y = (t >= off) ? buf[t - off] : 0;
        __syncthreads();
        buf[t] += y;
        __syncthreads();
    }
    if (i < N_NODES) offsets[i] = buf[t] - v;
    if (t == 255) partial[blockIdx.x] = buf[255];
}

__global__ void scan2_kernel(int* partial, int nb) {
    __shared__ int buf[256];
    int t = threadIdx.x;
    int v = (t < nb) ? partial[t] : 0;
    buf[t] = v;
    __syncthreads();
    for (int off = 1; off < 256; off <<= 1) {
        int y = (t >= off) ? buf[t - off] : 0;
        __syncthreads();
        buf[t] += y;
        __syncthreads();
    }
    if (t < nb) partial[t] = buf[t] - v;
}

__global__ void scan3_kernel(int* offsets, int* pos, const int* __restrict__ partial) {
    int i = blockIdx.x * 256 + threadIdx.x;
    if (i < N_NODES) {
        int o = offsets[i] + partial[i >> 8];
        offsets[i] = o;
        pos[i] = o;
    }
    if (i == 0) offsets[N_NODES] = N_EDGES + N_NODES;
}

__global__ void scatter_kernel(const int* __restrict__ ei, int* pos, int* csr_src) {
    int i = blockIdx.x * blockDim.x + threadIdx.x;
    if (i < N_EDGES) {
        int s = ei[i];
        int d = ei[N_EDGES + i];
        csr_src[atomicAdd(&pos[d], 1)] = s;
    } else if (i < N_EDGES + N_NODES) {
        int nn = i - N_EDGES;
        csr_src[atomicAdd(&pos[nn], 1)] = nn;
    }
}

// ------- scores for layer 0: one THREAD per node, vtab in LDS ---------
template <int K>
__global__ __launch_bounds__(256) void scores3_kernel(const __half* __restrict__ x,
                                                      const float* __restrict__ v,
                                                      float* __restrict__ ssrc,
                                                      float* __restrict__ sdst) {
    __shared__ float vs[K * 8];
    int t = threadIdx.x;
    for (int i = t; i < K * 8; i += 256) vs[i] = v[i];
    __syncthreads();
    int node = blockIdx.x * 256 + t;
    if (node >= N_NODES) return;
    const __half* xr = x + (size_t)node * K;
    f32x4 as = {0.f, 0.f, 0.f, 0.f};
    f32x4 ad = {0.f, 0.f, 0.f, 0.f};
    #pragma unroll 4
    for (int k0 = 0; k0 < K; k0 += 8) {
        uint4 u = *(const uint4*)(xr + k0);
        __half2* hp = (__half2*)&u;
        #pragma unroll
        for (int q = 0; q < 4; ++q) {
            float2 f = __half22float2(hp[q]);
            int k = k0 + 2 * q;
            as += f.x * *(const f32x4*)&vs[k * 8];
            ad += f.x * *(const f32x4*)&vs[k * 8 + 4];
            as += f.y * *(const f32x4*)&vs[(k + 1) * 8];
            ad += f.y * *(const f32x4*)&vs[(k + 1) * 8 + 4];
        }
    }
    *(f32x4*)(ssrc + node * 4) = as;
    *(f32x4*)(sdst + node * 4) = ad;
}

// ---- aggregate over INPUT features (linearity): agg[n][h*K+k] = sum_s alpha_h x_s[k]
// wave per node, 4 nodes/block. Gather 1KB wave-loads: EPR edges/round, uint4/lane.
// K=128: EPR=4 (16 lanes/edge); K=64: EPR=8 (8 lanes/edge).
template <int K>
__global__ __launch_bounds__(256) void aggregate_lin_kernel(const __half* __restrict__ tab16,
                                                            const float* __restrict__ s_src,
                                                            const float* __restrict__ s_dst,
                                                            const int* __restrict__ offsets,
                                                            const int* __restrict__ csr_src,
                                                            __half* __restrict__ agg) {
    constexpr int EPR = (K == 128) ? 4 : 8;
    constexpr int LPE = 64 / EPR;            // lanes per edge (16 or 8)
    int wv = threadIdx.x >> 6;
    int lane = threadIdx.x & 63;
    int n = blockIdx.x * 4 + wv;
    if (n >= N_NODES) return;
    int start = offsets[n], end = offsets[n + 1];
    int deg = end - start;
    const float4 sd = *(const float4*)(s_dst + n * 4);
    int cgrp = lane & (LPE - 1);             // channel group within edge
    int egoff = lane / LPE;                  // edge offset within round

    __shared__ int   roff[4][72];
    __shared__ float al[4][72][4];

    const char* xb = (const char*)tab16 + cgrp * 16;   // 8 halves per lane
    float acc[4][8] = {};

    // zero the pad region once
    if (lane < 8) {
        roff[wv][64 + lane] = 0;
        *(f32x4*)&al[wv][64 + lane][0] = f32x4{0.f, 0.f, 0.f, 0.f};
    }

    if (deg <= 64) {
        bool act = lane < deg;
        int src = act ? csr_src[start + lane] : 0;
        float4 ss = *(const float4*)(s_src + src * 4);
        float e0 = act ? lrelu(ss.x + sd.x) : -1e30f;
        float e1 = act ? lrelu(ss.y + sd.y) : -1e30f;
        float e2 = act ? lrelu(ss.z + sd.z) : -1e30f;
        float e3 = act ? lrelu(ss.w + sd.w) : -1e30f;
        float m0 = e0, m1 = e1, m2 = e2, m3 = e3;
        #pragma unroll
        for (int o = 32; o > 0; o >>= 1) {
            m0 = fmaxf(m0, __shfl_xor(m0, o));
            m1 = fmaxf(m1, __shfl_xor(m1, o));
            m2 = fmaxf(m2, __shfl_xor(m2, o));
            m3 = fmaxf(m3, __shfl_xor(m3, o));
        }
        float p0 = __expf(e0 - m0), p1 = __expf(e1 - m1);
        float p2 = __expf(e2 - m2), p3 = __expf(e3 - m3);
        float s0 = p0, s1 = p1, s2 = p2, s3 = p3;
        #pragma unroll
        for (int o = 32; o > 0; o >>= 1) {
            s0 += __shfl_xor(s0, o);
            s1 += __shfl_xor(s1, o);
            s2 += __shfl_xor(s2, o);
            s3 += __shfl_xor(s3, o);
        }
        f32x4 av = {p0 / s0, p1 / s1, p2 / s2, p3 / s3};
        roff[wv][lane] = src * (K * 2);
        *(f32x4*)&al[wv][lane][0] = av;
        wave_lds_fence();

        for (int j = 0; j < deg; j += EPR) {
            int eg = j + egoff;
            f32x4 a4 = *(const f32x4*)&al[wv][eg][0];
            uint4 u = *(const uint4*)(xb + roff[wv][eg]);
            __half2* hp = (__half2*)&u;
            #pragma unroll
            for (int q = 0; q < 4; ++q) {
                float2 f = __half22float2(hp[q]);
                #pragma unroll
                for (int h = 0; h < 4; ++h) {
                    acc[h][2 * q]     += a4[h] * f.x;
                    acc[h][2 * q + 1] += a4[h] * f.y;
                }
            }
        }
    } else {
        // generic chunked path (deg > 64): 3 passes
        float m0 = -1e30f, m1 = -1e30f, m2 = -1e30f, m3 = -1e30f;
        for (int j0 = 0; j0 < deg; j0 += 64) {
            int j = j0 + lane;
            bool act = j < deg;
            int src = act ? csr_src[start + j] : 0;
            float4 ss = *(const float4*)(s_src + src * 4);
            m0 = fmaxf(m0, act ? lrelu(ss.x + sd.x) : -1e30f);
            m1 = fmaxf(m1, act ? lrelu(ss.y + sd.y) : -1e30f);
            m2 = fmaxf(m2, act ? lrelu(ss.z + sd.z) : -1e30f);
            m3 = fmaxf(m3, act ? lrelu(ss.w + sd.w) : -1e30f);
        }
        #pragma unroll
        for (int o = 32; o > 0; o >>= 1) {
            m0 = fmaxf(m0, __shfl_xor(m0, o));
            m1 = fmaxf(m1, __shfl_xor(m1, o));
            m2 = fmaxf(m2, __shfl_xor(m2, o));
            m3 = fmaxf(m3, __shfl_xor(m3, o));
        }
        float s0 = 0.f, s1 = 0.f, s2 = 0.f, s3 = 0.f;
        for (int j0 = 0; j0 < deg; j0 += 64) {
            int j = j0 + lane;
            bool act = j < deg;
            int src = act ? csr_src[start + j] : 0;
            float4 ss = *(const float4*)(s_src + src * 4);
            s0 += act ? __expf(lrelu(ss.x + sd.x) - m0) : 0.f;
            s1 += act ? __expf(lrelu(ss.y + sd.y) - m1) : 0.f;
            s2 += act ? __expf(lrelu(ss.z + sd.z) - m2) : 0.f;
            s3 += act ? __expf(lrelu(ss.w + sd.w) - m3) : 0.f;
        }
        #pragma unroll
        for (int o = 32; o > 0; o >>= 1) {
            s0 += __shfl_xor(s0, o);
            s1 += __shfl_xor(s1, o);
            s2 += __shfl_xor(s2, o);
            s3 += __shfl_xor(s3, o);
        }
        float i0 = 1.f / s0, i1 = 1.f / s1, i2 = 1.f / s2, i3 = 1.f / s3;
        for (int j0 = 0; j0 < deg; j0 += 64) {
            int j = j0 + lane;
            bool act = j < deg;
            int src = act ? csr_src[start + j] : 0;
            float4 ss = *(const float4*)(s_src + src * 4);
            f32x4 av;
            av[0] = act ? __expf(lrelu(ss.x + sd.x) - m0) * i0 : 0.f;
            av[1] = act ? __expf(lrelu(ss.y + sd.y) - m1) * i1 : 0.f;
            av[2] = act ? __expf(lrelu(ss.z + sd.z) - m2) * i2 : 0.f;
            av[3] = act ? __expf(lrelu(ss.w + sd.w) - m3) * i3 : 0.f;
            roff[wv][lane] = act ? src * (K * 2) : 0;
            *(f32x4*)&al[wv][lane][0] = av;
            wave_lds_fence();
            int cend = min(64, deg - j0);
            for (int j2 = 0; j2 < cend; j2 += EPR) {
                int eg = j2 + egoff;
                f32x4 a4 = *(const f32x4*)&al[wv][eg][0];
                uint4 u = *(const uint4*)(xb + roff[wv][eg]);
                __half2* hp = (__half2*)&u;
                #pragma unroll
                for (int q = 0; q < 4; ++q) {
                    float2 f = __half22float2(hp[q]);
                    #pragma unroll
                    for (int h = 0; h < 4; ++h) {
                        acc[h][2 * q]     += a4[h] * f.x;
                        acc[h][2 * q + 1] += a4[h] * f.y;
                    }
                }
            }
            wave_lds_fence();
        }
    }

    // reduce across edge groups: lanes with same cgrp sum up
    #pragma unroll
    for (int stride = LPE; stride < 64; stride <<= 1) {
        #pragma unroll
        for (int h = 0; h < 4; ++h)
            #pragma unroll
            for (int r = 0; r < 8; ++r)
                acc[h][r] += __shfl_xor(acc[h][r], stride);
    }
    if (lane < LPE) {
        _Float16* ap = (_Float16*)agg + (size_t)n * (4 * K);
        #pragma unroll
        for (int h = 0; h < 4; ++h) {
            half8 v;
            #pragma unroll
            for (int r = 0; r < 8; ++r) v[r] = (_Float16)acc[h][r];
            *(half8*)(ap + h * K + cgrp * 8) = v;
        }
    }
}

// ------- epilogue GEMM: h16[N,128] = agg[N,KP] @ Wbig[KP,128] (+bias+BN+ReLU)
// + fused scores for next layer from the OUTPUT tile. BM=32, 256 thr, 4 waves.
template <int KP, bool SCORES>
__global__ __launch_bounds__(256) void gemm_ep_kernel(const __half* __restrict__ agg,
                                                      const _Float16* __restrict__ Wf,
                                                      const float* __restrict__ bias,
                                                      const float* __restrict__ gamma,
                                                      const float* __restrict__ beta,
                                                      const float* __restrict__ vtab_next,
                                                      __half* __restrict__ h16,
                                                      float* __restrict__ ssrc,
                                                      float* __restrict__ sdst) {
    __shared__ _Float16 As[32][KP + 8];
    __shared__ _Float16 tb[32][136];
    __shared__ float bn_s[3][HID];
    __shared__ float vs[SCORES ? HID * 8 : 8];
    int bm = blockIdx.x * 32;
    int t = threadIdx.x;
    int lane = t & 63;
    int w = t >> 6;
    int wm = w >> 1, wn = w & 1;
    int lr = lane & 15;
    int lk = (lane >> 4) * 8;
    int lg = lane >> 4;

    if (t < HID) {
        bn_s[0][t] = bias[t];
        bn_s[1][t] = gamma[t] * rsqrtf(1.f + 1e-5f);
        bn_s[2][t] = beta[t];
    }
    if (SCORES)
        for (int i = t; i < HID * 8; i += 256) vs[i] = vtab_next[i];
    {
        int row = t >> 3;
        #pragma unroll
        for (int it = 0; it < KP / 64; ++it) {
            int k8 = (t & 7) * 8 + it * 64;
            uint4 av = *(const uint4*)((const _Float16*)agg + (size_t)(bm + row) * KP + k8);
            *(uint4*)&As[row][k8] = av;
        }
    }
    __syncthreads();

    constexpr int NKg = KP / 32;
    f32x4 acc[4] = {};
    #pragma unroll
    for (int k0g = 0; k0g < NKg; ++k0g) {
        half8 af = *(const half8*)&As[wm * 16 + lr][k0g * 32 + lk];
        #pragma unroll
        for (int nn = 0; nn < 4; ++nn) {
            int cb = wn * 4 + nn;
            half8 bf = *(const half8*)(Wf + ((size_t)(cb * NKg + k0g) << 9) + lane * 8);
            acc[nn] = __builtin_amdgcn_mfma_f32_16x16x32_f16(af, bf, acc[nn], 0, 0, 0);
        }
    }

    // epilogue: bias + BN + ReLU -> tb
    #pragma unroll
    for (int nn = 0; nn < 4; ++nn) {
        int col = wn * 64 + nn * 16 + lr;
        float b = bn_s[0][col], g = bn_s[1][col], be = bn_s[2][col];
        #pragma unroll
        for (int r = 0; r < 4; ++r) {
            float o = acc[nn][r] + b;
            o = o * g + be;
            tb[wm * 16 + lg * 4 + r][col] = (_Float16)fmaxf(o, 0.f);
        }
    }
    __syncthreads();

    // coalesced h16 write: 32 rows x 128 cols
    {
        int row = t >> 3;
        int c0 = (t & 7) * 16;
        half8 v0 = *(const half8*)&tb[row][c0];
        half8 v1 = *(const half8*)&tb[row][c0 + 8];
        _Float16* cp = (_Float16*)h16 + (size_t)(bm + row) * HID + c0;
        *(half8*)(cp)     = v0;
        *(half8*)(cp + 8) = v1;
    }

    // fused scores for next layer from output tile
    if (SCORES) {
        int node = t >> 3, j = t & 7;
        float sacc = 0.f;
        #pragma unroll 2
        for (int k0 = 0; k0 < HID; k0 += 8) {
            half8 hv = *(const half8*)&tb[node][k0];
            #pragma unroll
            for (int e = 0; e < 8; ++e)
                sacc += (float)hv[e] * vs[(k0 + e) * 8 + j];
        }
        if (j < 4) ssrc[(bm + node) * 4 + j] = sacc;
        else       sdst[(bm + node) * 4 + (j - 4)] = sacc;
    }
}

// ------- pooling: 2 nodes in flight, uint (2-channel) loads ----------------
__global__ __launch_bounds__(128) void pool_kernel(const __half* __restrict__ h,
                                                   const int* __restrict__ batch,
                                                   float* pooled, float* counts) {
    int t = threadIdx.x;
    int which = t >> 6;
    int c2 = (t & 63) * 2;
    int n0 = blockIdx.x * 256 + which;
    int n1 = min(blockIdx.x * 256 + 256, N_NODES);
    if (n0 >= N_NODES) return;
    int cg = batch[n0];
    float a0 = 0.f, a1 = 0.f, cnt = 0.f;
    for (int n = n0; n < n1; n += 2) {
        int g = batch[n];
        if (g != cg) {
            atomicAdd(&pooled[cg * HID + c2], a0);
            atomicAdd(&pooled[cg * HID + c2 + 1], a1);
            if ((t & 63) == 0) atomicAdd(&counts[cg], cnt);
            a0 = 0.f; a1 = 0.f; cnt = 0.f; cg = g;
        }
        uint u = *(const uint*)(h + (size_t)n * HID + c2);
        __half2 hh = *(__half2*)&u;
        float2 f = __half22float2(hh);
        a0 += f.x; a1 += f.y; cnt += 1.f;
    }
    atomicAdd(&pooled[cg * HID + c2], a0);
    atomicAdd(&pooled[cg * HID + c2 + 1], a1);
    if ((t & 63) == 0) atomicAdd(&counts[cg], cnt);
}

// ---------------- head: mean-divide + fc1 + relu + fc2 ----------------
__global__ __launch_bounds__(128) void head_kernel(const float* __restrict__ pooled,
                                                   const float* __restrict__ counts,
                                                   const float* __restrict__ fc1_w,
                                                   const float* __restrict__ fc1_b,
                                                   const float* __restrict__ fc2_w,
                                                   const float* __restrict__ fc2_b,
                                                   float* __restrict__ out) {
    int gI = blockIdx.x;
    int t = threadIdx.x;
    __shared__ float p[HID], hb[HID];
    p[t] = pooled[gI * HID + t] / fmaxf(counts[gI], 1.f);
    __syncthreads();
    float a = fc1_b[t];
    #pragma unroll 4
    for (int k = 0; k < HID; ++k) a += p[k] * fc1_w[k * HID + t];
    hb[t] = fmaxf(a, 0.f);
    __syncthreads();
    if (t < OUTDIM) {
        float o = fc2_b[t];
        #pragma unroll 4
        for (int k = 0; k < HID; ++k) o += hb[k] * fc2_w[k * OUTDIM + t];
        out[gI * OUTDIM + t] = o;
    }
}

extern "C" void kernel_launch(void* const* d_in, const int* in_sizes, int n_in,
                              void* d_out, int out_size, void* d_ws, size_t ws_size,
                              hipStream_t stream) {
    const float* x     = (const float*)d_in[0];
    const int*   ei    = (const int*)d_in[1];
    const int*   batch = (const int*)d_in[2];
    const float* W[3]  = {(const float*)d_in[3],  (const float*)d_in[9],  (const float*)d_in[15]};
    const float* As[3] = {(const float*)d_in[4],  (const float*)d_in[10], (const float*)d_in[16]};
    const float* Ad[3] = {(const float*)d_in[5],  (const float*)d_in[11], (const float*)d_in[17]};
    const float* Bb[3] = {(const float*)d_in[6],  (const float*)d_in[12], (const float*)d_in[18]};
    const float* Gg[3] = {(const float*)d_in[7],  (const float*)d_in[13], (const float*)d_in[19]};
    const float* Be[3] = {(const float*)d_in[8],  (const float*)d_in[14], (const float*)d_in[20]};
    const float* fc1_w = (const float*)d_in[21];
    const float* fc1_b = (const float*)d_in[22];
    const float* fc2_w = (const float*)d_in[23];
    const float* fc2_b = (const float*)d_in[24];

    char* ws = (char*)d_ws;
    size_t off = 0;
    auto alloc = [&](size_t bytes) {
        void* p = ws + off;
        off = (off + bytes + 255) & ~(size_t)255;
        return p;
    };
    __half* agg    = (__half*)alloc((size_t)N_NODES * NCOLS * 2);   // [N][4*K] fp16
    __half* x16    = (__half*)alloc((size_t)N_NODES * FIN * 2);
    __half* h16    = (__half*)alloc((size_t)N_NODES * HID * 2);
    _Float16* Wf[3];
    Wf[0] = (_Float16*)alloc((size_t)(4 * FIN) * HID * 2);
    Wf[1] = (_Float16*)alloc((size_t)(4 * HID) * HID * 2);
    Wf[2] = (_Float16*)alloc((size_t)(4 * HID) * HID * 2);
    float* vtab[3];
    vtab[0] = (float*)alloc((size_t)FIN * 8 * 4);
    vtab[1] = (float*)alloc((size_t)HID * 8 * 4);
    vtab[2] = (float*)alloc((size_t)HID * 8 * 4);
    float* ssrc    = (float*)alloc((size_t)N_NODES * HEADS * 4);
    float* sdst    = (float*)alloc((size_t)N_NODES * HEADS * 4);
    int*   deg     = (int*)alloc((size_t)N_NODES * 4);
    int*   offsets = (int*)alloc((size_t)(N_NODES + 1) * 4);
    int*   pos     = (int*)alloc((size_t)N_NODES * 4);
    int*   partial = (int*)alloc((size_t)256 * 4);
    int*   csr     = (int*)alloc((size_t)(N_EDGES + N_NODES) * 4);
    float* pooled  = (float*)alloc((size_t)NGROUPS * HID * 4 + (size_t)NGROUPS * 4);
    float* counts  = pooled + (size_t)NGROUPS * HID;

    // fused prep: x16 + fragment-major Wbig + vtab
    const int PREP_TOTAL = PREP_X4 + PREP_WSWZ + PREP_V;
    prep_kernel<<<(PREP_TOTAL + 255) / 256, 256, 0, stream>>>(
        x, x16, W[0], W[1], W[2], Wf[0], Wf[1], Wf[2],
        As[0], Ad[0], As[1], Ad[1], As[2], Ad[2], vtab[0], vtab[1], vtab[2]);

    // CSR by dst (with self loops)
    const int NB = (N_NODES + 255) / 256;   // 157
    hipMemsetAsync(deg, 0, (size_t)N_NODES * 4, stream);
    deg_count_kernel<<<(N_EDGES + 255) / 256, 256, 0, stream>>>(ei, deg);
    scan1_kernel<<<NB, 256, 0, stream>>>(deg, offsets, partial);
    scan2_kernel<<<1, 256, 0, stream>>>(partial, NB);
    scan3_kernel<<<NB, 256, 0, stream>>>(offsets, pos, partial);
    scatter_kernel<<<(N_EDGES + N_NODES + 255) / 256, 256, 0, stream>>>(ei, pos, csr);

    // layer-0 scores from x16
    scores3_kernel<64><<<NB, 256, 0, stream>>>(x16, vtab[0], ssrc, sdst);

    // layer 0: aggregate inputs (K=64) then epilogue GEMM (KP=256) + scores for l1
    aggregate_lin_kernel<64><<<(N_NODES + 3) / 4, 256, 0, stream>>>(
        x16, ssrc, sdst, offsets, csr, agg);
    gemm_ep_kernel<256, true><<<N_NODES / 32, 256, 0, stream>>>(
        agg, Wf[0], Bb[0], Gg[0], Be[0], vtab[1], h16, ssrc, sdst);

    // layer 1
    aggregate_lin_kernel<128><<<(N_NODES + 3) / 4, 256, 0, stream>>>(
        h16, ssrc, sdst, offsets, csr, agg);
    gemm_ep_kernel<512, true><<<N_NODES / 32, 256, 0, stream>>>(
        agg, Wf[1], Bb[1], Gg[1], Be[1], vtab[2], h16, ssrc, sdst);

    // layer 2 (no next-layer scores)
    aggregate_lin_kernel<128><<<(N_NODES + 3) / 4, 256, 0, stream>>>(
        h16, ssrc, sdst, offsets, csr, agg);
    gemm_ep_kernel<512, false><<<N_NODES / 32, 256, 0, stream>>>(
        agg, Wf[2], Bb[2], Gg[2], Be[2], nullptr, h16, nullptr, nullptr);

    // global mean pool + MLP head
    hipMemsetAsync(pooled, 0, (size_t)NGROUPS * HID * 4 + (size_t)NGROUPS * 4, stream);
    pool_kernel<<<(N_NODES + 255) / 256, 128, 0, stream>>>(h16, batch, pooled, counts);
    head_kernel<<<NGROUPS, 128, 0, stream>>>(pooled, counts, fc1_w, fc1_b, fc2_w, fc2_b,
                                             (float*)d_out);
}